// Round 3
// 455.527 us; speedup vs baseline: 1.0359x; 1.0359x over previous
//
#include <hip/hip_runtime.h>

// Problem constants: B=8, S=2048, N=4, D=1024.
// out[b,s,i,d] = (sum_j h_res[b,s,i,j] * x[b,s,j,d]) * h_out[b,s,d]
//             + h_post[b,s,i] * x[b,s,i,d]
//
// Pure streaming kernel: ~572 MB total traffic, ~92 us floor at 6.3 TB/s.
//
// v2b: same as v2 but with clang ext_vector_type for the 16B streaming
// accesses — __builtin_nontemporal_load/store reject HIP's float4 (it is a
// HIP_vector_type class, not a native vector).
//
// Structure: barrier-free. v1 staged the 20 block-uniform coefficients
// through LDS + __syncthreads(); hipcc drains vmcnt(0)/lgkmcnt(0) before
// s_barrier, so the 5 big per-lane loads could not issue until the tiny
// coefficient load had round-tripped HBM -> two serialized memory latencies
// per block. Now every thread loads the coefficients directly (block-uniform
// address -> wave-broadcast); all loads are independent and overlap fully.
// Streaming data uses nontemporal hints (touched exactly once; keep it out
// of L2/L3).

#define NB 8
#define NS 2048
#define NN 4
#define ND 1024

typedef float v4f __attribute__((ext_vector_type(4)));

__global__ __launch_bounds__(256) void fused_stream_mix(
    const float* __restrict__ x,      // [B*S, N, D]
    const float* __restrict__ h_res,  // [B*S, N, N]
    const float* __restrict__ h_out,  // [B*S, D]
    const float* __restrict__ h_post, // [B*S, N]
    float* __restrict__ out)          // [B*S, N, D]
{
    const int bs = blockIdx.x;        // 0 .. B*S-1
    const int t  = threadIdx.x;       // 0 .. 255 ; owns d = 4t .. 4t+3

    // Big streaming loads first: 4 x-rows + h_out, 80 B/lane in flight.
    const v4f* __restrict__ xp = (const v4f*)(x + (size_t)bs * NN * ND);
    const v4f x0 = __builtin_nontemporal_load(xp + 0 * (ND / 4) + t);
    const v4f x1 = __builtin_nontemporal_load(xp + 1 * (ND / 4) + t);
    const v4f x2 = __builtin_nontemporal_load(xp + 2 * (ND / 4) + t);
    const v4f x3 = __builtin_nontemporal_load(xp + 3 * (ND / 4) + t);
    const v4f ho = __builtin_nontemporal_load(
        (const v4f*)(h_out + (size_t)bs * ND) + t);

    // Block-uniform coefficients: direct loads, no LDS, no barrier.
    // Same address across the wave -> single transaction + broadcast.
    const float* __restrict__ hr = h_res  + (size_t)bs * (NN * NN);
    const float* __restrict__ hq = h_post + (size_t)bs * NN;
    float r[NN * NN];
    float p[NN];
    #pragma unroll
    for (int k = 0; k < NN * NN; ++k) r[k] = hr[k];
    #pragma unroll
    for (int i = 0; i < NN; ++i) p[i] = hq[i];

    v4f* __restrict__ op = (v4f*)(out + (size_t)bs * NN * ND);

    #pragma unroll
    for (int i = 0; i < NN; ++i) {
        const float r0 = r[i * NN + 0];
        const float r1 = r[i * NN + 1];
        const float r2 = r[i * NN + 2];
        const float r3 = r[i * NN + 3];
        const float hp = p[i];
        const v4f xi = (i == 0) ? x0 : (i == 1) ? x1 : (i == 2) ? x2 : x3;

        v4f m;
        m.x = (r0 * x0.x + r1 * x1.x + r2 * x2.x + r3 * x3.x) * ho.x + hp * xi.x;
        m.y = (r0 * x0.y + r1 * x1.y + r2 * x2.y + r3 * x3.y) * ho.y + hp * xi.y;
        m.z = (r0 * x0.z + r1 * x1.z + r2 * x2.z + r3 * x3.z) * ho.z + hp * xi.z;
        m.w = (r0 * x0.w + r1 * x1.w + r2 * x2.w + r3 * x3.w) * ho.w + hp * xi.w;

        __builtin_nontemporal_store(m, op + i * (ND / 4) + t);
    }
}

extern "C" void kernel_launch(void* const* d_in, const int* in_sizes, int n_in,
                              void* d_out, int out_size, void* d_ws, size_t ws_size,
                              hipStream_t stream) {
    const float* x      = (const float*)d_in[0];
    const float* h_res  = (const float*)d_in[1];
    const float* h_out  = (const float*)d_in[2];
    const float* h_post = (const float*)d_in[3];
    float* out = (float*)d_out;

    // One block per (b,s) position; 256 threads cover D=1024 as float4.
    fused_stream_mix<<<NB * NS, 256, 0, stream>>>(x, h_res, h_out, h_post, out);
}

// Round 4
// 455.143 us; speedup vs baseline: 1.0368x; 1.0008x over previous
//
#include <hip/hip_runtime.h>

// Problem constants: B=8, S=2048, N=4, D=1024.
// out[b,s,i,d] = (sum_j h_res[b,s,i,j] * x[b,s,j,d]) * h_out[b,s,d]
//             + h_post[b,s,i] * x[b,s,i,d]
//
// ~605 MB total traffic -> ~96 us floor at the 6.29 TB/s measured copy ceiling.
//
// v3: persistent grid-stride blocks with software-pipelined double-buffer.
// v2b (one-shot blocks, ~128 us) left ~25% on the table: 16384 short-lived
// blocks each stall ~900cy on HBM with bursty issue and per-block launch/
// drain overhead, plus 20 scalar coefficient loads per thread. Now: 1024
// resident blocks (4/CU via __launch_bounds__(256,4)), 16 iterations each;
// iteration k+1's loads (5 nt streams + coefficients vectorized to 5 x v4f)
// are issued BEFORE iteration k's compute+store, so the load queue never
// drains. nt hints kept from v2b (held constant for attribution).

#define NB 8
#define NS 2048
#define NN 4
#define ND 1024
#define GRID 1024
#define ITER ((NB * NS) / GRID)   // 16

typedef float v4f __attribute__((ext_vector_type(4)));

struct Streams {
    v4f x0, x1, x2, x3;  // one float4 slice of each of the 4 x-rows
    v4f ho;              // h_out slice
    v4f r0, r1, r2, r3;  // h_res rows (r_i = coefficients for output row i)
    v4f p;               // h_post
};

__device__ __forceinline__ void load_bs(int bs, int t,
                                        const float* __restrict__ x,
                                        const float* __restrict__ h_res,
                                        const float* __restrict__ h_out,
                                        const float* __restrict__ h_post,
                                        Streams& s)
{
    const v4f* __restrict__ xp = (const v4f*)(x + (size_t)bs * NN * ND);
    s.x0 = __builtin_nontemporal_load(xp + 0 * (ND / 4) + t);
    s.x1 = __builtin_nontemporal_load(xp + 1 * (ND / 4) + t);
    s.x2 = __builtin_nontemporal_load(xp + 2 * (ND / 4) + t);
    s.x3 = __builtin_nontemporal_load(xp + 3 * (ND / 4) + t);
    s.ho = __builtin_nontemporal_load((const v4f*)(h_out + (size_t)bs * ND) + t);
    // Block-uniform coefficients, vectorized: 5 VMEM instrs instead of 20.
    const v4f* __restrict__ hr = (const v4f*)(h_res + (size_t)bs * (NN * NN));
    s.r0 = hr[0]; s.r1 = hr[1]; s.r2 = hr[2]; s.r3 = hr[3];
    s.p  = *(const v4f*)(h_post + (size_t)bs * NN);
}

__device__ __forceinline__ void compute_store(int bs, int t, const Streams& s,
                                              float* __restrict__ out)
{
    v4f* __restrict__ op = (v4f*)(out + (size_t)bs * NN * ND);
    #pragma unroll
    for (int i = 0; i < NN; ++i) {
        const v4f rr = (i == 0) ? s.r0 : (i == 1) ? s.r1 : (i == 2) ? s.r2 : s.r3;
        const v4f xi = (i == 0) ? s.x0 : (i == 1) ? s.x1 : (i == 2) ? s.x2 : s.x3;
        const float hp = s.p[i];

        v4f m;
        m.x = (rr.x * s.x0.x + rr.y * s.x1.x + rr.z * s.x2.x + rr.w * s.x3.x) * s.ho.x + hp * xi.x;
        m.y = (rr.x * s.x0.y + rr.y * s.x1.y + rr.z * s.x2.y + rr.w * s.x3.y) * s.ho.y + hp * xi.y;
        m.z = (rr.x * s.x0.z + rr.y * s.x1.z + rr.z * s.x2.z + rr.w * s.x3.z) * s.ho.z + hp * xi.z;
        m.w = (rr.x * s.x0.w + rr.y * s.x1.w + rr.z * s.x2.w + rr.w * s.x3.w) * s.ho.w + hp * xi.w;

        __builtin_nontemporal_store(m, op + i * (ND / 4) + t);
    }
}

__global__ __launch_bounds__(256, 4) void fused_stream_mix(
    const float* __restrict__ x,      // [B*S, N, D]
    const float* __restrict__ h_res,  // [B*S, N, N]
    const float* __restrict__ h_out,  // [B*S, D]
    const float* __restrict__ h_post, // [B*S, N]
    float* __restrict__ out)          // [B*S, N, D]
{
    const int b = blockIdx.x;   // 0 .. GRID-1
    const int t = threadIdx.x;  // 0 .. 255 ; owns d = 4t .. 4t+3

    Streams cur, nxt;
    load_bs(b, t, x, h_res, h_out, h_post, cur);

    #pragma unroll
    for (int k = 0; k < ITER; ++k) {
        if (k + 1 < ITER)
            load_bs(b + (k + 1) * GRID, t, x, h_res, h_out, h_post, nxt);
        compute_store(b + k * GRID, t, cur, out);
        if (k + 1 < ITER)
            cur = nxt;  // fully unrolled -> pure SSA renaming, no moves
    }
}

extern "C" void kernel_launch(void* const* d_in, const int* in_sizes, int n_in,
                              void* d_out, int out_size, void* d_ws, size_t ws_size,
                              hipStream_t stream) {
    const float* x      = (const float*)d_in[0];
    const float* h_res  = (const float*)d_in[1];
    const float* h_out  = (const float*)d_in[2];
    const float* h_post = (const float*)d_in[3];
    float* out = (float*)d_out;

    // 1024 persistent blocks (4/CU, all resident), 16 bs-positions each.
    fused_stream_mix<<<GRID, 256, 0, stream>>>(x, h_res, h_out, h_post, out);
}